// Round 4
// baseline (257.985 us; speedup 1.0000x reference)
//
#include <hip/hip_runtime.h>

#define TPB  256
#define NBLK 2048

// y is exactly 0.0f or 1.0f; -(y*log(p) + (1-y)*log1p(-p)) reduces to a select.
__device__ __forceinline__ float bce1(float p, float y) {
    return (y > 0.5f) ? -__logf(p) : -__logf(1.0f - p);
}
__device__ __forceinline__ float bce4(float4 p, float4 y) {
    return bce1(p.x, y.x) + bce1(p.y, y.y) + bce1(p.z, y.z) + bce1(p.w, y.w);
}

__global__ void __launch_bounds__(TPB) hml_fused(
    const float* __restrict__ l1p, const float* __restrict__ l2pCC,
    const float* __restrict__ l2pURW,
    const float* __restrict__ p3a, const float* __restrict__ p3b,
    const float* __restrict__ p3c, const float* __restrict__ p3d,
    const float* __restrict__ p3e,
    const float* __restrict__ l1y, const float* __restrict__ l2yCC,
    const float* __restrict__ l2yURW,
    const float* __restrict__ y3a, const float* __restrict__ y3b,
    const float* __restrict__ y3c, const float* __restrict__ y3d,
    const float* __restrict__ y3e,
    int nrows, double* __restrict__ acc, unsigned int* __restrict__ done,
    float* __restrict__ out)
{
    double s1 = 0, s2cc = 0, s2urw = 0, s3 = 0, nCC = 0, nURW = 0, n3 = 0;
    const int  tid = blockIdx.x * blockDim.x + threadIdx.x;
    const long T   = (long)gridDim.x * blockDim.x;

    // ---------- phase A: level1 + level2 + n3 count (1 row per thread) ----------
    for (long i = tid; i < nrows; i += T) {
        float2 p1 = ((const float2*)l1p)[i];
        float2 y1 = ((const float2*)l1y)[i];
        float2 pu = ((const float2*)l2pURW)[i];
        float2 yu = ((const float2*)l2yURW)[i];
        float c0p = l2pCC[i*3+0], c1p = l2pCC[i*3+1], c2p = l2pCC[i*3+2];
        float c0y = l2yCC[i*3+0], c1y = l2yCC[i*3+1], c2y = l2yCC[i*3+2];

        s1 += (double)(bce1(p1.x, y1.x) + bce1(p1.y, y1.y));

        const bool aCC  = (y1.x > 0.5f);
        const bool aURW = (y1.y > 0.5f);
        const float fCC  = aCC  ? 1.f : 0.f;
        const float fURW = aURW ? 1.f : 0.f;

        s2cc  += (double)(fCC  * (bce1(c0p, c0y) + bce1(c1p, c1y) + bce1(c2p, c2y)));
        s2urw += (double)(fURW * (bce1(pu.x, yu.x) + bce1(pu.y, yu.y)));
        nCC   += (double)fCC;
        nURW  += (double)fURW;

        n3 += (double)(((aCC  && c0y  != 0.f) ? 1 : 0) +
                       ((aCC  && c1y  != 0.f) ? 1 : 0) +
                       ((aCC  && c2y  != 0.f) ? 1 : 0) +
                       ((aURW && yu.x != 0.f) ? 1 : 0) +
                       ((aURW && yu.y != 0.f) ? 1 : 0));
    }

    // ---------- phase B: level3, unconditional streaming, 4x unrolled ----------
    const long nvec = (long)nrows * 8;   // 32 floats/row = 8 float4

    const float4* P[5] = { (const float4*)p3a, (const float4*)p3b, (const float4*)p3c,
                           (const float4*)p3d, (const float4*)p3e };
    const float4* Q[5] = { (const float4*)y3a, (const float4*)y3b, (const float4*)y3c,
                           (const float4*)y3d, (const float4*)y3e };

    #pragma unroll
    for (int e = 0; e < 5; ++e) {
        const float4* __restrict__ p4  = P[e];
        const float4* __restrict__ q4  = Q[e];
        const float*  __restrict__ lab = (e < 3) ? l2yCC : l2yURW;
        const int w   = (e < 3) ? 3 : 2;
        const int col = (e < 3) ? e : e - 3;
        const int br  = (e < 3) ? 0 : 1;

        for (long v = tid; v < nvec; v += 4 * T) {
            const long v1 = v + T, v2 = v + 2 * T, v3 = v + 3 * T;
            const bool g1 = v1 < nvec, g2 = v2 < nvec, g3 = v3 < nvec;
            const long r0 = v >> 3, r1 = v1 >> 3, r2 = v2 >> 3, r3 = v3 >> 3;

            // mask inputs (independent small-array loads; 8 lanes/row -> broadcast)
            float a0 = l1y[r0*2 + br];
            float c0 = lab[r0*w + col];
            float a1 = 0.f, c1 = 0.f, a2 = 0.f, c2 = 0.f, a3 = 0.f, c3 = 0.f;
            if (g1) { a1 = l1y[r1*2 + br]; c1 = lab[r1*w + col]; }
            if (g2) { a2 = l1y[r2*2 + br]; c2 = lab[r2*w + col]; }
            if (g3) { a3 = l1y[r3*2 + br]; c3 = lab[r3*w + col]; }

            // 8 independent 16B payload loads issued before any use
            float4 pa = p4[v],  qa = q4[v];
            float4 pb, qb, pc, qc, pd, qd;
            if (g1) { pb = p4[v1]; qb = q4[v1]; }
            if (g2) { pc = p4[v2]; qc = q4[v2]; }
            if (g3) { pd = p4[v3]; qd = q4[v3]; }

            const float m0 = (a0 > 0.5f && c0 != 0.f) ? 1.f : 0.f;
            const float m1 = (a1 > 0.5f && c1 != 0.f) ? 1.f : 0.f;
            const float m2 = (a2 > 0.5f && c2 != 0.f) ? 1.f : 0.f;
            const float m3 = (a3 > 0.5f && c3 != 0.f) ? 1.f : 0.f;

            float s = m0 * bce4(pa, qa);
            if (g1) s += m1 * bce4(pb, qb);
            if (g2) s += m2 * bce4(pc, qc);
            if (g3) s += m3 * bce4(pd, qd);
            s3 += (double)s;
        }
    }

    // ---------- block reduction: 7 doubles -> global atomics ----------
    double vals[7] = { s1, s2cc, s2urw, s3, nCC, nURW, n3 };
    __shared__ double sm[4][7];
    const int lane = threadIdx.x & 63;
    const int wid  = threadIdx.x >> 6;

    #pragma unroll
    for (int j = 0; j < 7; ++j) {
        double x = vals[j];
        #pragma unroll
        for (int o = 32; o > 0; o >>= 1)
            x += __shfl_down(x, o, 64);
        if (lane == 0) sm[wid][j] = x;
    }
    __syncthreads();

    if (threadIdx.x == 0) {
        #pragma unroll
        for (int j = 0; j < 7; ++j)
            atomicAdd(&acc[j], sm[0][j] + sm[1][j] + sm[2][j] + sm[3][j]);

        // last-block finalize (device-scope atomics; G16-safe)
        __threadfence();
        if (atomicAdd(done, 1u) == gridDim.x - 1) {
            double S1   = atomicAdd(&acc[0], 0.0);
            double S2cc = atomicAdd(&acc[1], 0.0);
            double S2u  = atomicAdd(&acc[2], 0.0);
            double S3   = atomicAdd(&acc[3], 0.0);
            double NCC  = atomicAdd(&acc[4], 0.0);
            double NU   = atomicAdd(&acc[5], 0.0);
            double N3   = atomicAdd(&acc[6], 0.0);

            double level1 = S1 / ((double)nrows * 2.0);
            double l2 = 0.0;
            if (NCC > 0.0) l2 += S2cc / (NCC * 3.0);
            if (NU  > 0.0) l2 += S2u  / (NU  * 2.0);
            double level2 = 0.5 * l2;
            double level3 = (N3 > 0.0) ? (S3 / 32.0) / N3 : 0.0;

            out[0] = (float)(level1 + level2 + level3);
        }
    }
}

extern "C" void kernel_launch(void* const* d_in, const int* in_sizes, int n_in,
                              void* d_out, int out_size, void* d_ws, size_t ws_size,
                              hipStream_t stream) {
    const float* l1p   = (const float*)d_in[0];
    const float* l2pCC = (const float*)d_in[1];
    const float* l2pURW= (const float*)d_in[2];
    const float* p3a   = (const float*)d_in[3];
    const float* p3b   = (const float*)d_in[4];
    const float* p3c   = (const float*)d_in[5];
    const float* p3d   = (const float*)d_in[6];
    const float* p3e   = (const float*)d_in[7];
    const float* l1y   = (const float*)d_in[8];
    const float* l2yCC = (const float*)d_in[9];
    const float* l2yURW= (const float*)d_in[10];
    const float* y3a   = (const float*)d_in[11];
    const float* y3b   = (const float*)d_in[12];
    const float* y3c   = (const float*)d_in[13];
    const float* y3d   = (const float*)d_in[14];
    const float* y3e   = (const float*)d_in[15];

    const int nrows = in_sizes[0] / 2;

    double*       acc  = (double*)d_ws;
    unsigned int* done = (unsigned int*)((char*)d_ws + 56);

    hipMemsetAsync(d_ws, 0, 64, stream);

    hml_fused<<<NBLK, TPB, 0, stream>>>(
        l1p, l2pCC, l2pURW, p3a, p3b, p3c, p3d, p3e,
        l1y, l2yCC, l2yURW, y3a, y3b, y3c, y3d, y3e,
        nrows, acc, done, (float*)d_out);
}

// Round 5
// 239.272 us; speedup vs baseline: 1.0782x; 1.0782x over previous
//
#include <hip/hip_runtime.h>

#define TPB  256
#define NBLK 2048

// y is exactly 0.0f or 1.0f; -(y*log(p) + (1-y)*log1p(-p)) reduces to a select.
__device__ __forceinline__ float bce1(float p, float y) {
    return (y > 0.5f) ? -__logf(p) : -__logf(1.0f - p);
}
__device__ __forceinline__ float bce4(float4 p, float4 y) {
    return bce1(p.x, y.x) + bce1(p.y, y.y) + bce1(p.z, y.z) + bce1(p.w, y.w);
}

__global__ void hml_fused(
    const float* __restrict__ l1p, const float* __restrict__ l2pCC,
    const float* __restrict__ l2pURW,
    const float* __restrict__ p3a, const float* __restrict__ p3b,
    const float* __restrict__ p3c, const float* __restrict__ p3d,
    const float* __restrict__ p3e,
    const float* __restrict__ l1y, const float* __restrict__ l2yCC,
    const float* __restrict__ l2yURW,
    const float* __restrict__ y3a, const float* __restrict__ y3b,
    const float* __restrict__ y3c, const float* __restrict__ y3d,
    const float* __restrict__ y3e,
    int nrows, double* __restrict__ acc, unsigned int* __restrict__ done,
    float* __restrict__ out)
{
    double s1 = 0, s2cc = 0, s2urw = 0, s3 = 0, nCC = 0, nURW = 0, n3 = 0;
    const int  tid = blockIdx.x * blockDim.x + threadIdx.x;
    const long T   = (long)gridDim.x * blockDim.x;

    // ---------- phase A: level1 + level2 + n3 count (per row) ----------
    for (long i = tid; i < nrows; i += T) {
        float2 p1 = ((const float2*)l1p)[i];
        float2 y1 = ((const float2*)l1y)[i];
        float2 pu = ((const float2*)l2pURW)[i];
        float2 yu = ((const float2*)l2yURW)[i];
        float c0p = l2pCC[i*3+0], c1p = l2pCC[i*3+1], c2p = l2pCC[i*3+2];
        float c0y = l2yCC[i*3+0], c1y = l2yCC[i*3+1], c2y = l2yCC[i*3+2];

        s1 += (double)(bce1(p1.x, y1.x) + bce1(p1.y, y1.y));

        const bool aCC  = (y1.x > 0.5f);
        const bool aURW = (y1.y > 0.5f);
        const float fCC  = aCC  ? 1.f : 0.f;
        const float fURW = aURW ? 1.f : 0.f;

        s2cc  += (double)(fCC  * (bce1(c0p, c0y) + bce1(c1p, c1y) + bce1(c2p, c2y)));
        s2urw += (double)(fURW * (bce1(pu.x, yu.x) + bce1(pu.y, yu.y)));
        nCC   += (double)fCC;
        nURW  += (double)fURW;

        n3 += (double)(((aCC  && c0y  != 0.f) ? 1 : 0) +
                       ((aCC  && c1y  != 0.f) ? 1 : 0) +
                       ((aCC  && c2y  != 0.f) ? 1 : 0) +
                       ((aURW && yu.x != 0.f) ? 1 : 0) +
                       ((aURW && yu.y != 0.f) ? 1 : 0));
    }

    // ---------- phase B: level3 — all 5 entries interleaved per vec index ----------
    // 10 UNCONDITIONAL independent float4 loads per iteration (160 B/lane in
    // flight, no guards, no predication) + small mask-input loads consumed only
    // as multiplier operands. Zero branches in the body.
    const long nvec = (long)nrows * 8;   // 32 floats/row = 8 float4

    const float4* __restrict__ P0 = (const float4*)p3a;
    const float4* __restrict__ P1 = (const float4*)p3b;
    const float4* __restrict__ P2 = (const float4*)p3c;
    const float4* __restrict__ P3 = (const float4*)p3d;
    const float4* __restrict__ P4 = (const float4*)p3e;
    const float4* __restrict__ Q0 = (const float4*)y3a;
    const float4* __restrict__ Q1 = (const float4*)y3b;
    const float4* __restrict__ Q2 = (const float4*)y3c;
    const float4* __restrict__ Q3 = (const float4*)y3d;
    const float4* __restrict__ Q4 = (const float4*)y3e;

    for (long v = tid; v < nvec; v += T) {
        const long row = v >> 3;

        // payload loads first: 10 independent dwordx4, nothing gates them
        float4 pa = P0[v], pb = P1[v], pc = P2[v], pd = P3[v], pe = P4[v];
        float4 qa = Q0[v], qb = Q1[v], qc = Q2[v], qd = Q3[v], qe = Q4[v];

        // mask inputs (independent, L2/L3-resident; 8 lanes/row broadcast)
        float2 y1 = ((const float2*)l1y)[row];
        float2 yu = ((const float2*)l2yURW)[row];
        float  c0 = l2yCC[row*3+0];
        float  c1 = l2yCC[row*3+1];
        float  c2 = l2yCC[row*3+2];

        const float aCC  = (y1.x > 0.5f) ? 1.f : 0.f;
        const float aURW = (y1.y > 0.5f) ? 1.f : 0.f;
        const float m0 = (c0   != 0.f) ? aCC  : 0.f;
        const float m1 = (c1   != 0.f) ? aCC  : 0.f;
        const float m2 = (c2   != 0.f) ? aCC  : 0.f;
        const float m3 = (yu.x != 0.f) ? aURW : 0.f;
        const float m4 = (yu.y != 0.f) ? aURW : 0.f;

        float s = m0 * bce4(pa, qa)
                + m1 * bce4(pb, qb)
                + m2 * bce4(pc, qc)
                + m3 * bce4(pd, qd)
                + m4 * bce4(pe, qe);
        s3 += (double)s;
    }

    // ---------- block reduction: 7 doubles -> global atomics ----------
    double vals[7] = { s1, s2cc, s2urw, s3, nCC, nURW, n3 };
    __shared__ double sm[4][7];
    const int lane = threadIdx.x & 63;
    const int wid  = threadIdx.x >> 6;

    #pragma unroll
    for (int j = 0; j < 7; ++j) {
        double x = vals[j];
        #pragma unroll
        for (int o = 32; o > 0; o >>= 1)
            x += __shfl_down(x, o, 64);
        if (lane == 0) sm[wid][j] = x;
    }
    __syncthreads();

    if (threadIdx.x == 0) {
        #pragma unroll
        for (int j = 0; j < 7; ++j)
            atomicAdd(&acc[j], sm[0][j] + sm[1][j] + sm[2][j] + sm[3][j]);

        // last-block finalize (device-scope atomics; G16-safe)
        __threadfence();
        if (atomicAdd(done, 1u) == gridDim.x - 1) {
            double S1   = atomicAdd(&acc[0], 0.0);
            double S2cc = atomicAdd(&acc[1], 0.0);
            double S2u  = atomicAdd(&acc[2], 0.0);
            double S3   = atomicAdd(&acc[3], 0.0);
            double NCC  = atomicAdd(&acc[4], 0.0);
            double NU   = atomicAdd(&acc[5], 0.0);
            double N3   = atomicAdd(&acc[6], 0.0);

            double level1 = S1 / ((double)nrows * 2.0);
            double l2 = 0.0;
            if (NCC > 0.0) l2 += S2cc / (NCC * 3.0);
            if (NU  > 0.0) l2 += S2u  / (NU  * 2.0);
            double level2 = 0.5 * l2;
            double level3 = (N3 > 0.0) ? (S3 / 32.0) / N3 : 0.0;

            out[0] = (float)(level1 + level2 + level3);
        }
    }
}

extern "C" void kernel_launch(void* const* d_in, const int* in_sizes, int n_in,
                              void* d_out, int out_size, void* d_ws, size_t ws_size,
                              hipStream_t stream) {
    const float* l1p   = (const float*)d_in[0];
    const float* l2pCC = (const float*)d_in[1];
    const float* l2pURW= (const float*)d_in[2];
    const float* p3a   = (const float*)d_in[3];
    const float* p3b   = (const float*)d_in[4];
    const float* p3c   = (const float*)d_in[5];
    const float* p3d   = (const float*)d_in[6];
    const float* p3e   = (const float*)d_in[7];
    const float* l1y   = (const float*)d_in[8];
    const float* l2yCC = (const float*)d_in[9];
    const float* l2yURW= (const float*)d_in[10];
    const float* y3a   = (const float*)d_in[11];
    const float* y3b   = (const float*)d_in[12];
    const float* y3c   = (const float*)d_in[13];
    const float* y3d   = (const float*)d_in[14];
    const float* y3e   = (const float*)d_in[15];

    const int nrows = in_sizes[0] / 2;

    double*       acc  = (double*)d_ws;
    unsigned int* done = (unsigned int*)((char*)d_ws + 56);

    hipMemsetAsync(d_ws, 0, 64, stream);

    hml_fused<<<NBLK, TPB, 0, stream>>>(
        l1p, l2pCC, l2pURW, p3a, p3b, p3c, p3d, p3e,
        l1y, l2yCC, l2yURW, y3a, y3b, y3c, y3d, y3e,
        nrows, acc, done, (float*)d_out);
}